// Round 5
// baseline (893.246 us; speedup 1.0000x reference)
//
#include <hip/hip_runtime.h>
#include <hip/hip_bf16.h>

#define N_NODES 65536
#define N_EDGES 1048576
#define IN_DIM 96
#define HID 128
#define OUTD 256
#define N_ACT 20
#define NPB_MLP 8    // nodes per block, k_mlp (128 thr)
#define NPB_PROJ 16  // nodes per block, k_proj (256 thr)

typedef unsigned short u16;
typedef unsigned int u32;

// intermediates stored as bf16 to halve gather traffic; all math in fp32
__device__ __forceinline__ float bf2f(u16 v) { return __uint_as_float(((u32)v) << 16); }
__device__ __forceinline__ u16 f2bf(float f) {
    u32 x = __float_as_uint(f);
    return (u16)((x + 0x7fffu + ((x >> 16) & 1u)) >> 16);
}

__device__ __forceinline__ float wsum(float v) {
#pragma unroll
    for (int o = 32; o > 0; o >>= 1) v += __shfl_xor(v, o, 64);
    return v;
}

// block of 128 threads (2 waves): reduce (s, q) across block
__device__ __forceinline__ void block_reduce2_128(float& s, float& q, float* red) {
#pragma unroll
    for (int o = 32; o > 0; o >>= 1) { s += __shfl_xor(s, o, 64); q += __shfl_xor(q, o, 64); }
    int tid = threadIdx.x;
    __syncthreads();
    if ((tid & 63) == 0) { red[(tid >> 6) * 2] = s; red[(tid >> 6) * 2 + 1] = q; }
    __syncthreads();
    s = red[0] + red[2];
    q = red[1] + red[3];
}

// ---------------- zero deg+cursor ----------------
__global__ __launch_bounds__(256) void k_zero(int* __restrict__ p) {
    p[blockIdx.x * 256 + threadIdx.x] = 0;
}

// ---------------- degree count ----------------
__global__ __launch_bounds__(256) void k_deg(const int* __restrict__ ei, int* __restrict__ deg) {
    int e = blockIdx.x * 256 + threadIdx.x;
    atomicAdd(deg + ei[N_EDGES + e], 1);
}

// ---------------- exclusive scan of degrees -> CSR offsets ----------------
__global__ __launch_bounds__(1024) void k_scan(const int* __restrict__ deg, int* __restrict__ off) {
    __shared__ int part[1024];
    int t = threadIdx.x;
    int base = t * 64;
    int s = 0;
    for (int i = 0; i < 64; i++) s += deg[base + i];
    part[t] = s;
    __syncthreads();
    for (int o = 1; o < 1024; o <<= 1) {
        int v = (t >= o) ? part[t - o] : 0;
        __syncthreads();
        part[t] += v;
        __syncthreads();
    }
    int run = (t == 0) ? 0 : part[t - 1];
    for (int i = 0; i < 64; i++) {
        off[base + i] = run;
        run += deg[base + i];
    }
    if (t == 1023) off[N_NODES] = run;
}

// ---------------- scatter edge records (src + 3 attrs) into CSR order ----------------
__global__ __launch_bounds__(256) void k_scatter(
    const int* __restrict__ ei, const float* __restrict__ ea,
    const int* __restrict__ off, int* __restrict__ cursor,
    int4* __restrict__ erec)
{
    int e = blockIdx.x * 256 + threadIdx.x;
    int src = ei[e];
    int dst = ei[N_EDGES + e];
    float a0 = ea[e * 3 + 0];
    float a1 = ea[e * 3 + 1];
    float a2 = ea[e * 3 + 2];
    int pos = off[dst] + atomicAdd(cursor + dst, 1);
    erec[pos] = make_int4(src, __float_as_int(a0), __float_as_int(a1), __float_as_int(a2));
}

// ---------------- MLP (96 -> 128 -> 128, relu+LN each), fp32 in, bf16 out ----------------
__global__ __launch_bounds__(128) void k_mlp(
    const float* __restrict__ in,
    const float* __restrict__ W0, const float* __restrict__ b0,
    const float* __restrict__ g0, const float* __restrict__ be0,
    const float* __restrict__ W1, const float* __restrict__ b1,
    const float* __restrict__ g1, const float* __restrict__ be1,
    u16* __restrict__ x1out)
{
    int tid = threadIdx.x;
    int n0 = blockIdx.x * NPB_MLP;
    __shared__ float xin[NPB_MLP][IN_DIM];
    __shared__ float x0[NPB_MLP][HID];
    __shared__ float red[4];

    for (int i = tid; i < NPB_MLP * IN_DIM; i += 128)
        ((float*)xin)[i] = in[(long)n0 * IN_DIM + i];
    __syncthreads();

    float acc[NPB_MLP];
    // layer 0
    {
        float bb = b0[tid];
#pragma unroll
        for (int i = 0; i < NPB_MLP; i++) acc[i] = bb;
        for (int k = 0; k < IN_DIM; k++) {
            float w = W0[k * HID + tid];
#pragma unroll
            for (int i = 0; i < NPB_MLP; i++) acc[i] = fmaf(xin[i][k], w, acc[i]);
        }
        float gv = g0[tid], bev = be0[tid];
        for (int i = 0; i < NPB_MLP; i++) {
            float a = fmaxf(acc[i], 0.f);
            float s = a, q = a * a;
            block_reduce2_128(s, q, red);
            float mu = s * (1.f / HID);
            float var = q * (1.f / HID) - mu * mu;
            float rs = rsqrtf(fmaxf(var, 0.f) + 1e-5f);
            x0[i][tid] = (a - mu) * rs * gv + bev;
        }
    }
    __syncthreads();

    // layer 1
    {
        float bb = b1[tid];
#pragma unroll
        for (int i = 0; i < NPB_MLP; i++) acc[i] = bb;
        for (int k = 0; k < HID; k++) {
            float w = W1[k * HID + tid];
#pragma unroll
            for (int i = 0; i < NPB_MLP; i++) acc[i] = fmaf(x0[i][k], w, acc[i]);
        }
        float gv = g1[tid], bev = be1[tid];
        for (int i = 0; i < NPB_MLP; i++) {
            float a = fmaxf(acc[i], 0.f);
            float s = a, q = a * a;
            block_reduce2_128(s, q, red);
            float mu = s * (1.f / HID);
            float var = q * (1.f / HID) - mu * mu;
            float rs = rsqrtf(fmaxf(var, 0.f) + 1e-5f);
            x1out[(long)(n0 + i) * HID + tid] = f2bf((a - mu) * rs * gv + bev);
        }
    }
}

// ---------------- projections xl, xr, residual (all bf16 out), 16 nodes/block ----------------
__global__ __launch_bounds__(256) void k_proj(
    const u16* __restrict__ x1,
    const float* __restrict__ Wl, const float* __restrict__ bl,
    const float* __restrict__ Wr, const float* __restrict__ br,
    const float* __restrict__ Wres, const float* __restrict__ gbias,
    u16* __restrict__ xl, u16* __restrict__ xr, u16* __restrict__ hres)
{
    int j = threadIdx.x;
    int n0 = blockIdx.x * NPB_PROJ;
    __shared__ float x[NPB_PROJ][HID];
    for (int i = j; i < NPB_PROJ * HID; i += 256)
        ((float*)x)[i] = bf2f(x1[(long)n0 * HID + i]);
    __syncthreads();

    float a[NPB_PROJ], b[NPB_PROJ], c[NPB_PROJ];
    float bla = bl[j], bra = br[j], gba = gbias[j];
#pragma unroll
    for (int i = 0; i < NPB_PROJ; i++) { a[i] = bla; b[i] = bra; c[i] = gba; }

    for (int k = 0; k < HID; k++) {
        float wl = Wl[k * OUTD + j];
        float wr = Wr[k * OUTD + j];
        float wq = Wres[k * OUTD + j];
#pragma unroll
        for (int i = 0; i < NPB_PROJ; i++) {
            float xv = x[i][k];
            a[i] = fmaf(xv, wl, a[i]);
            b[i] = fmaf(xv, wr, b[i]);
            c[i] = fmaf(xv, wq, c[i]);
        }
    }
#pragma unroll
    for (int i = 0; i < NPB_PROJ; i++) {
        long row = (long)(n0 + i) * OUTD + j;
        xl[row] = f2bf(a[i]);
        xr[row] = f2bf(b[i]);
        hres[row] = f2bf(c[i]);
    }
}

// ---------------- fused aggregation, 4-edge batched online softmax ----------------
// 1 wave per node; lanes cover 256 dims (4 each). 4 xl gathers in flight,
// 4 interleaved butterflies (6-deep), grouped softmax rescale.
__global__ __launch_bounds__(256) void k_agg_fused(
    const int* __restrict__ off, const int4* __restrict__ erec,
    const u16* __restrict__ xl, const u16* __restrict__ xr, const u16* __restrict__ hres,
    const float* __restrict__ We, const float* __restrict__ att,
    const float* __restrict__ g2, const float* __restrict__ be2,
    const float* __restrict__ Wq, const float* __restrict__ bq,
    float* __restrict__ out)
{
    int wid = threadIdx.x >> 6, lane = threadIdx.x & 63;
    int n = blockIdx.x * 4 + wid;
    int j0 = lane * 4;
    __shared__ float lds[4][OUTD + 4];

    // loop-invariant per-lane constants (broadcast, L1-resident)
    float4 w0 = *(const float4*)(We + j0);
    float4 w1 = *(const float4*)(We + OUTD + j0);
    float4 w2 = *(const float4*)(We + 2 * OUTD + j0);
    float4 av = *(const float4*)(att + j0);

    ushort4 xrv = *(const ushort4*)(xr + (long)n * OUTD + j0);
    float xr0 = bf2f(xrv.x), xr1 = bf2f(xrv.y), xr2 = bf2f(xrv.z), xr3 = bf2f(xrv.w);

    int beg = off[n], end = off[n + 1];

    float m = -3.0e38f, s = 0.f;
    float a0 = 0.f, a1 = 0.f, a2 = 0.f, a3 = 0.f;

    for (int i = beg; i < end; i += 4) {
        // clamped record loads (broadcast address -> single line each)
        int i1 = (i + 1 < end) ? i + 1 : i;
        int i2 = (i + 2 < end) ? i + 2 : i;
        int i3 = (i + 3 < end) ? i + 3 : i;
        int4 r0 = erec[i];
        int4 r1 = erec[i1];
        int4 r2 = erec[i2];
        int4 r3 = erec[i3];

        // 4 independent row gathers in flight
        ushort4 v0 = *(const ushort4*)(xl + (long)r0.x * OUTD + j0);
        ushort4 v1 = *(const ushort4*)(xl + (long)r1.x * OUTD + j0);
        ushort4 v2 = *(const ushort4*)(xl + (long)r2.x * OUTD + j0);
        ushort4 v3 = *(const ushort4*)(xl + (long)r3.x * OUTD + j0);

        float x00 = bf2f(v0.x), x01 = bf2f(v0.y), x02 = bf2f(v0.z), x03 = bf2f(v0.w);
        float x10 = bf2f(v1.x), x11 = bf2f(v1.y), x12 = bf2f(v1.z), x13 = bf2f(v1.w);
        float x20 = bf2f(v2.x), x21 = bf2f(v2.y), x22 = bf2f(v2.z), x23 = bf2f(v2.w);
        float x30 = bf2f(v3.x), x31 = bf2f(v3.y), x32 = bf2f(v3.z), x33 = bf2f(v3.w);

        float p0, p1, p2, p3;
        {
            float ea0 = __int_as_float(r0.y), ea1 = __int_as_float(r0.z), ea2 = __int_as_float(r0.w);
            float t0 = x00 + xr0 + ea0 * w0.x + ea1 * w1.x + ea2 * w2.x;
            float t1 = x01 + xr1 + ea0 * w0.y + ea1 * w1.y + ea2 * w2.y;
            float t2 = x02 + xr2 + ea0 * w0.z + ea1 * w1.z + ea2 * w2.z;
            float t3 = x03 + xr3 + ea0 * w0.w + ea1 * w1.w + ea2 * w2.w;
            p0 = fmaxf(t0, 0.2f * t0) * av.x;
            p0 = fmaf(fmaxf(t1, 0.2f * t1), av.y, p0);
            p0 = fmaf(fmaxf(t2, 0.2f * t2), av.z, p0);
            p0 = fmaf(fmaxf(t3, 0.2f * t3), av.w, p0);
        }
        {
            float ea0 = __int_as_float(r1.y), ea1 = __int_as_float(r1.z), ea2 = __int_as_float(r1.w);
            float t0 = x10 + xr0 + ea0 * w0.x + ea1 * w1.x + ea2 * w2.x;
            float t1 = x11 + xr1 + ea0 * w0.y + ea1 * w1.y + ea2 * w2.y;
            float t2 = x12 + xr2 + ea0 * w0.z + ea1 * w1.z + ea2 * w2.z;
            float t3 = x13 + xr3 + ea0 * w0.w + ea1 * w1.w + ea2 * w2.w;
            p1 = fmaxf(t0, 0.2f * t0) * av.x;
            p1 = fmaf(fmaxf(t1, 0.2f * t1), av.y, p1);
            p1 = fmaf(fmaxf(t2, 0.2f * t2), av.z, p1);
            p1 = fmaf(fmaxf(t3, 0.2f * t3), av.w, p1);
        }
        {
            float ea0 = __int_as_float(r2.y), ea1 = __int_as_float(r2.z), ea2 = __int_as_float(r2.w);
            float t0 = x20 + xr0 + ea0 * w0.x + ea1 * w1.x + ea2 * w2.x;
            float t1 = x21 + xr1 + ea0 * w0.y + ea1 * w1.y + ea2 * w2.y;
            float t2 = x22 + xr2 + ea0 * w0.z + ea1 * w1.z + ea2 * w2.z;
            float t3 = x23 + xr3 + ea0 * w0.w + ea1 * w1.w + ea2 * w2.w;
            p2 = fmaxf(t0, 0.2f * t0) * av.x;
            p2 = fmaf(fmaxf(t1, 0.2f * t1), av.y, p2);
            p2 = fmaf(fmaxf(t2, 0.2f * t2), av.z, p2);
            p2 = fmaf(fmaxf(t3, 0.2f * t3), av.w, p2);
        }
        {
            float ea0 = __int_as_float(r3.y), ea1 = __int_as_float(r3.z), ea2 = __int_as_float(r3.w);
            float t0 = x30 + xr0 + ea0 * w0.x + ea1 * w1.x + ea2 * w2.x;
            float t1 = x31 + xr1 + ea0 * w0.y + ea1 * w1.y + ea2 * w2.y;
            float t2 = x32 + xr2 + ea0 * w0.z + ea1 * w1.z + ea2 * w2.z;
            float t3 = x33 + xr3 + ea0 * w0.w + ea1 * w1.w + ea2 * w2.w;
            p3 = fmaxf(t0, 0.2f * t0) * av.x;
            p3 = fmaf(fmaxf(t1, 0.2f * t1), av.y, p3);
            p3 = fmaf(fmaxf(t2, 0.2f * t2), av.z, p3);
            p3 = fmaf(fmaxf(t3, 0.2f * t3), av.w, p3);
        }

        // 4 interleaved butterflies: 24 shuffles, 6-deep latency
#pragma unroll
        for (int o = 32; o > 0; o >>= 1) {
            p0 += __shfl_xor(p0, o, 64);
            p1 += __shfl_xor(p1, o, 64);
            p2 += __shfl_xor(p2, o, 64);
            p3 += __shfl_xor(p3, o, 64);
        }

        // invalidate tail edges (their exp underflows to 0)
        if (i + 1 >= end) p1 = -3.0e38f;
        if (i + 2 >= end) p2 = -3.0e38f;
        if (i + 3 >= end) p3 = -3.0e38f;

        // grouped online-softmax update
        float mn = fmaxf(fmaxf(fmaxf(m, p0), fmaxf(p1, p2)), p3);
        float fac = __expf(m - mn);        // first group: exp(-huge) -> 0
        float e0 = __expf(p0 - mn);
        float e1 = __expf(p1 - mn);
        float e2 = __expf(p2 - mn);
        float e3 = __expf(p3 - mn);
        s = fmaf(s, fac, e0 + e1 + e2 + e3);
        a0 = a0 * fac; a0 = fmaf(e0, x00, a0); a0 = fmaf(e1, x10, a0); a0 = fmaf(e2, x20, a0); a0 = fmaf(e3, x30, a0);
        a1 = a1 * fac; a1 = fmaf(e0, x01, a1); a1 = fmaf(e1, x11, a1); a1 = fmaf(e2, x21, a1); a1 = fmaf(e3, x31, a1);
        a2 = a2 * fac; a2 = fmaf(e0, x02, a2); a2 = fmaf(e1, x12, a2); a2 = fmaf(e2, x22, a2); a2 = fmaf(e3, x32, a2);
        a3 = a3 * fac; a3 = fmaf(e0, x03, a3); a3 = fmaf(e1, x13, a3); a3 = fmaf(e2, x23, a3); a3 = fmaf(e3, x33, a3);
        m = mn;
    }

    float inv = (end > beg) ? 1.f / s : 0.f;

    ushort4 hv = *(const ushort4*)(hres + (long)n * OUTD + j0);
    float h0 = fmaxf(fmaf(a0, inv, bf2f(hv.x)), 0.f);
    float h1 = fmaxf(fmaf(a1, inv, bf2f(hv.y)), 0.f);
    float h2 = fmaxf(fmaf(a2, inv, bf2f(hv.z)), 0.f);
    float h3 = fmaxf(fmaf(a3, inv, bf2f(hv.w)), 0.f);

    float sum = h0 + h1 + h2 + h3;
    float sq = h0 * h0 + h1 * h1 + h2 * h2 + h3 * h3;
#pragma unroll
    for (int o = 32; o > 0; o >>= 1) {
        sum += __shfl_xor(sum, o, 64);
        sq += __shfl_xor(sq, o, 64);
    }
    float mu = sum * (1.f / OUTD);
    float var = sq * (1.f / OUTD) - mu * mu;
    float rs = rsqrtf(fmaxf(var, 0.f) + 1e-5f);

    float4 gv = *(const float4*)(g2 + j0);
    float4 bv = *(const float4*)(be2 + j0);
    lds[wid][j0 + 0] = (h0 - mu) * rs * gv.x + bv.x;
    lds[wid][j0 + 1] = (h1 - mu) * rs * gv.y + bv.y;
    lds[wid][j0 + 2] = (h2 - mu) * rs * gv.z + bv.z;
    lds[wid][j0 + 3] = (h3 - mu) * rs * gv.w + bv.w;
    __syncthreads();

    if (lane < N_ACT) {
        float qv = bq[lane];
#pragma unroll 4
        for (int j = 0; j < OUTD; j++) qv = fmaf(lds[wid][j], Wq[j * N_ACT + lane], qv);
        out[(long)n * N_ACT + lane] = qv;
    }
}

extern "C" void kernel_launch(void* const* d_in, const int* in_sizes, int n_in,
                              void* d_out, int out_size, void* d_ws, size_t ws_size,
                              hipStream_t stream) {
    (void)in_sizes; (void)n_in; (void)out_size; (void)ws_size;
    const float* inp  = (const float*)d_in[0];
    const int*   ei   = (const int*)d_in[1];
    const float* ea   = (const float*)d_in[2];
    const float* W0   = (const float*)d_in[3];
    const float* b0   = (const float*)d_in[4];
    const float* g0   = (const float*)d_in[5];
    const float* be0  = (const float*)d_in[6];
    const float* W1   = (const float*)d_in[7];
    const float* b1   = (const float*)d_in[8];
    const float* g1   = (const float*)d_in[9];
    const float* be1  = (const float*)d_in[10];
    const float* Wl   = (const float*)d_in[11];
    const float* bl   = (const float*)d_in[12];
    const float* Wr   = (const float*)d_in[13];
    const float* br   = (const float*)d_in[14];
    const float* We   = (const float*)d_in[15];
    const float* att  = (const float*)d_in[16];
    const float* Wres = (const float*)d_in[17];
    const float* gbias= (const float*)d_in[18];
    const float* g2   = (const float*)d_in[19];
    const float* be2  = (const float*)d_in[20];
    const float* Wq   = (const float*)d_in[21];
    const float* bq   = (const float*)d_in[22];
    float* out = (float*)d_out;

    char* ws = (char*)d_ws;
    size_t o = 0;
    auto alloc = [&](size_t bytes) -> void* {
        void* p = ws + o;
        o += (bytes + 255) & ~(size_t)255;
        return p;
    };
    // total ~129 MiB
    u16*   x1     = (u16*)  alloc((size_t)N_NODES * HID * 2);     // 16 MiB
    u16*   xl     = (u16*)  alloc((size_t)N_NODES * OUTD * 2);    // 32 MiB
    u16*   xr     = (u16*)  alloc((size_t)N_NODES * OUTD * 2);    // 32 MiB
    u16*   hres   = (u16*)  alloc((size_t)N_NODES * OUTD * 2);    // 32 MiB
    int*   deg    = (int*)  alloc((size_t)N_NODES * 4);           // 256 KiB
    int*   cursor = (int*)  alloc((size_t)N_NODES * 4);           // 256 KiB (contiguous with deg)
    int*   off    = (int*)  alloc((size_t)(N_NODES + 1) * 4);
    int4*  erec   = (int4*) alloc((size_t)N_EDGES * 16);          // 16 MiB

    k_zero<<<(2 * N_NODES) / 256, 256, 0, stream>>>(deg);  // zeroes deg + cursor
    k_deg<<<N_EDGES / 256, 256, 0, stream>>>(ei, deg);
    k_scan<<<1, 1024, 0, stream>>>(deg, off);
    k_scatter<<<N_EDGES / 256, 256, 0, stream>>>(ei, ea, off, cursor, erec);
    k_mlp<<<N_NODES / NPB_MLP, 128, 0, stream>>>(inp, W0, b0, g0, be0, W1, b1, g1, be1, x1);
    k_proj<<<N_NODES / NPB_PROJ, 256, 0, stream>>>(x1, Wl, bl, Wr, br, Wres, gbias, xl, xr, hres);
    k_agg_fused<<<N_NODES / 4, 256, 0, stream>>>(off, erec, xl, xr, hres, We, att, g2, be2, Wq, bq, out);
}

// Round 6
// 793.925 us; speedup vs baseline: 1.1251x; 1.1251x over previous
//
#include <hip/hip_runtime.h>
#include <hip/hip_bf16.h>

#define N_NODES 65536
#define N_EDGES 1048576
#define IN_DIM 96
#define HID 128
#define OUTD 256
#define N_ACT 20
#define NPB_MLP 8    // nodes per block, k_mlp (128 thr)

typedef unsigned short u16;
typedef unsigned int u32;
typedef __attribute__((ext_vector_type(8))) short bf16x8;
typedef __attribute__((ext_vector_type(4))) float f32x4;

// intermediates stored as bf16; all math in fp32
__device__ __forceinline__ float bf2f(u16 v) { return __uint_as_float(((u32)v) << 16); }
__device__ __forceinline__ u16 f2bf(float f) {
    u32 x = __float_as_uint(f);
    return (u16)((x + 0x7fffu + ((x >> 16) & 1u)) >> 16);
}

// block of 128 threads (2 waves): reduce (s, q) across block
__device__ __forceinline__ void block_reduce2_128(float& s, float& q, float* red) {
#pragma unroll
    for (int o = 32; o > 0; o >>= 1) { s += __shfl_xor(s, o, 64); q += __shfl_xor(q, o, 64); }
    int tid = threadIdx.x;
    __syncthreads();
    if ((tid & 63) == 0) { red[(tid >> 6) * 2] = s; red[(tid >> 6) * 2 + 1] = q; }
    __syncthreads();
    s = red[0] + red[2];
    q = red[1] + red[3];
}

// ---------------- zero deg+cursor ----------------
__global__ __launch_bounds__(256) void k_zero(int* __restrict__ p) {
    p[blockIdx.x * 256 + threadIdx.x] = 0;
}

// ---------------- degree count ----------------
__global__ __launch_bounds__(256) void k_deg(const int* __restrict__ ei, int* __restrict__ deg) {
    int e = blockIdx.x * 256 + threadIdx.x;
    atomicAdd(deg + ei[N_EDGES + e], 1);
}

// ---------------- exclusive scan of degrees -> CSR offsets ----------------
__global__ __launch_bounds__(1024) void k_scan(const int* __restrict__ deg, int* __restrict__ off) {
    __shared__ int part[1024];
    int t = threadIdx.x;
    int base = t * 64;
    int s = 0;
    for (int i = 0; i < 64; i++) s += deg[base + i];
    part[t] = s;
    __syncthreads();
    for (int o = 1; o < 1024; o <<= 1) {
        int v = (t >= o) ? part[t - o] : 0;
        __syncthreads();
        part[t] += v;
        __syncthreads();
    }
    int run = (t == 0) ? 0 : part[t - 1];
    for (int i = 0; i < 64; i++) {
        off[base + i] = run;
        run += deg[base + i];
    }
    if (t == 1023) off[N_NODES] = run;
}

// ---------------- scatter edge records (src + 3 attrs) into CSR order ----------------
__global__ __launch_bounds__(256) void k_scatter(
    const int* __restrict__ ei, const float* __restrict__ ea,
    const int* __restrict__ off, int* __restrict__ cursor,
    int4* __restrict__ erec)
{
    int e = blockIdx.x * 256 + threadIdx.x;
    int src = ei[e];
    int dst = ei[N_EDGES + e];
    float a0 = ea[e * 3 + 0];
    float a1 = ea[e * 3 + 1];
    float a2 = ea[e * 3 + 2];
    int pos = off[dst] + atomicAdd(cursor + dst, 1);
    erec[pos] = make_int4(src, __float_as_int(a0), __float_as_int(a1), __float_as_int(a2));
}

// ---------------- convert+transpose GAT weights to bf16, n-major [768][128] ----------------
// n in [0,256): Wl column n; [256,512): Wr; [512,768): Wres
__global__ __launch_bounds__(256) void k_cvtw(
    const float* __restrict__ Wl, const float* __restrict__ Wr, const float* __restrict__ Wres,
    u16* __restrict__ wt)
{
    int idx = blockIdx.x * 256 + threadIdx.x;   // 0 .. 98303
    int n = idx >> 7;
    int k = idx & 127;
    float v;
    if (n < 256) v = Wl[k * OUTD + n];
    else if (n < 512) v = Wr[k * OUTD + (n - 256)];
    else v = Wres[k * OUTD + (n - 512)];
    wt[idx] = f2bf(v);
}

// ---------------- MLP (96 -> 128 -> 128, relu+LN each), fp32 in, bf16 out ----------------
__global__ __launch_bounds__(128) void k_mlp(
    const float* __restrict__ in,
    const float* __restrict__ W0, const float* __restrict__ b0,
    const float* __restrict__ g0, const float* __restrict__ be0,
    const float* __restrict__ W1, const float* __restrict__ b1,
    const float* __restrict__ g1, const float* __restrict__ be1,
    u16* __restrict__ x1out)
{
    int tid = threadIdx.x;
    int n0 = blockIdx.x * NPB_MLP;
    __shared__ float xin[NPB_MLP][IN_DIM];
    __shared__ float x0[NPB_MLP][HID];
    __shared__ float red[4];

    for (int i = tid; i < NPB_MLP * IN_DIM; i += 128)
        ((float*)xin)[i] = in[(long)n0 * IN_DIM + i];
    __syncthreads();

    float acc[NPB_MLP];
    // layer 0
    {
        float bb = b0[tid];
#pragma unroll
        for (int i = 0; i < NPB_MLP; i++) acc[i] = bb;
        for (int k = 0; k < IN_DIM; k++) {
            float w = W0[k * HID + tid];
#pragma unroll
            for (int i = 0; i < NPB_MLP; i++) acc[i] = fmaf(xin[i][k], w, acc[i]);
        }
        float gv = g0[tid], bev = be0[tid];
        for (int i = 0; i < NPB_MLP; i++) {
            float a = fmaxf(acc[i], 0.f);
            float s = a, q = a * a;
            block_reduce2_128(s, q, red);
            float mu = s * (1.f / HID);
            float var = q * (1.f / HID) - mu * mu;
            float rs = rsqrtf(fmaxf(var, 0.f) + 1e-5f);
            x0[i][tid] = (a - mu) * rs * gv + bev;
        }
    }
    __syncthreads();

    // layer 1
    {
        float bb = b1[tid];
#pragma unroll
        for (int i = 0; i < NPB_MLP; i++) acc[i] = bb;
        for (int k = 0; k < HID; k++) {
            float w = W1[k * HID + tid];
#pragma unroll
            for (int i = 0; i < NPB_MLP; i++) acc[i] = fmaf(x0[i][k], w, acc[i]);
        }
        float gv = g1[tid], bev = be1[tid];
        for (int i = 0; i < NPB_MLP; i++) {
            float a = fmaxf(acc[i], 0.f);
            float s = a, q = a * a;
            block_reduce2_128(s, q, red);
            float mu = s * (1.f / HID);
            float var = q * (1.f / HID) - mu * mu;
            float rs = rsqrtf(fmaxf(var, 0.f) + 1e-5f);
            x1out[(long)(n0 + i) * HID + tid] = f2bf((a - mu) * rs * gv + bev);
        }
    }
}

// ---------------- MFMA projections: [xl|xr|hres] = x1 @ [Wl|Wr|Wres] + bias ----------------
// Block: 4 waves, each wave a 16-row M-subtile x 256 cols. Grid.y selects tensor.
// A-frag: A[m=lane&15][k=quad*8+j] -> contiguous 16B from x1 (row-major, K=128).
// B-frag: B[k=quad*8+j][n=lane&15] -> contiguous 16B from wt (n-major, [768][128]).
// C/D: col=lane&15, row=quad*4+reg (m89/m91-verified layout).
__global__ __launch_bounds__(256, 4) void k_proj_mfma(
    const u16* __restrict__ x1, const u16* __restrict__ wt,
    const float* __restrict__ bl, const float* __restrict__ br, const float* __restrict__ gbias,
    u16* __restrict__ xl, u16* __restrict__ xr, u16* __restrict__ hres)
{
    int wid = threadIdx.x >> 6, lane = threadIdx.x & 63;
    int m0 = (blockIdx.x * 4 + wid) * 16;
    int nT = blockIdx.y;           // 0:xl 1:xr 2:hres
    int r = lane & 15;
    int q = lane >> 4;

    f32x4 acc[16];
#pragma unroll
    for (int t = 0; t < 16; t++) acc[t] = {0.f, 0.f, 0.f, 0.f};

    const u16* arow = x1 + (long)(m0 + r) * HID + q * 8;
    const u16* wbase = wt + (long)(nT * 256 + r) * HID + q * 8;
#pragma unroll
    for (int k0 = 0; k0 < HID; k0 += 32) {
        bf16x8 afrag = *(const bf16x8*)(arow + k0);
#pragma unroll
        for (int t = 0; t < 16; t++) {
            bf16x8 bfrag = *(const bf16x8*)(wbase + (long)t * 16 * HID + k0);
            acc[t] = __builtin_amdgcn_mfma_f32_16x16x32_bf16(afrag, bfrag, acc[t], 0, 0, 0);
        }
    }

    const float* bias = (nT == 0) ? bl : (nT == 1) ? br : gbias;
    u16* dst = (nT == 0) ? xl : (nT == 1) ? xr : hres;
#pragma unroll
    for (int t = 0; t < 16; t++) {
        int col = t * 16 + r;
        float bv = bias[col];
#pragma unroll
        for (int g = 0; g < 4; g++) {
            int row = m0 + q * 4 + g;
            dst[(long)row * OUTD + col] = f2bf(acc[t][g] + bv);
        }
    }
}

// ---------------- fused aggregation: plain-exp softmax (no max-sub; |p|<~10 by LN), ----------------
// 2 edges/iter, 1 wave/node, residual + relu/LN + 256->20 head.
__global__ __launch_bounds__(256, 6) void k_agg_fused(
    const int* __restrict__ off, const int4* __restrict__ erec,
    const u16* __restrict__ xl, const u16* __restrict__ xr, const u16* __restrict__ hres,
    const float* __restrict__ We, const float* __restrict__ att,
    const float* __restrict__ g2, const float* __restrict__ be2,
    const float* __restrict__ Wq, const float* __restrict__ bq,
    float* __restrict__ out)
{
    int wid = threadIdx.x >> 6, lane = threadIdx.x & 63;
    int n = blockIdx.x * 4 + wid;
    int j0 = lane * 4;
    __shared__ float lds[4][OUTD + 4];

    float4 w0 = *(const float4*)(We + j0);
    float4 w1 = *(const float4*)(We + OUTD + j0);
    float4 w2 = *(const float4*)(We + 2 * OUTD + j0);
    float4 av = *(const float4*)(att + j0);

    ushort4 xrv = *(const ushort4*)(xr + (long)n * OUTD + j0);
    float xr0 = bf2f(xrv.x), xr1 = bf2f(xrv.y), xr2 = bf2f(xrv.z), xr3 = bf2f(xrv.w);

    int beg = off[n], end = off[n + 1];

    float s = 0.f;
    float a0 = 0.f, a1 = 0.f, a2 = 0.f, a3 = 0.f;

    for (int i = beg; i < end; i += 2) {
        int i1 = (i + 1 < end) ? i + 1 : i;
        int4 r0 = erec[i];
        int4 r1 = erec[i1];

        ushort4 v0 = *(const ushort4*)(xl + (long)r0.x * OUTD + j0);
        ushort4 v1 = *(const ushort4*)(xl + (long)r1.x * OUTD + j0);

        float x00 = bf2f(v0.x), x01 = bf2f(v0.y), x02 = bf2f(v0.z), x03 = bf2f(v0.w);
        float x10 = bf2f(v1.x), x11 = bf2f(v1.y), x12 = bf2f(v1.z), x13 = bf2f(v1.w);

        float p0, p1;
        {
            float ea0 = __int_as_float(r0.y), ea1 = __int_as_float(r0.z), ea2 = __int_as_float(r0.w);
            float t0 = x00 + xr0 + ea0 * w0.x + ea1 * w1.x + ea2 * w2.x;
            float t1 = x01 + xr1 + ea0 * w0.y + ea1 * w1.y + ea2 * w2.y;
            float t2 = x02 + xr2 + ea0 * w0.z + ea1 * w1.z + ea2 * w2.z;
            float t3 = x03 + xr3 + ea0 * w0.w + ea1 * w1.w + ea2 * w2.w;
            p0 = fmaxf(t0, 0.2f * t0) * av.x;
            p0 = fmaf(fmaxf(t1, 0.2f * t1), av.y, p0);
            p0 = fmaf(fmaxf(t2, 0.2f * t2), av.z, p0);
            p0 = fmaf(fmaxf(t3, 0.2f * t3), av.w, p0);
        }
        {
            float ea0 = __int_as_float(r1.y), ea1 = __int_as_float(r1.z), ea2 = __int_as_float(r1.w);
            float t0 = x10 + xr0 + ea0 * w0.x + ea1 * w1.x + ea2 * w2.x;
            float t1 = x11 + xr1 + ea0 * w0.y + ea1 * w1.y + ea2 * w2.y;
            float t2 = x12 + xr2 + ea0 * w0.z + ea1 * w1.z + ea2 * w2.z;
            float t3 = x13 + xr3 + ea0 * w0.w + ea1 * w1.w + ea2 * w2.w;
            p1 = fmaxf(t0, 0.2f * t0) * av.x;
            p1 = fmaf(fmaxf(t1, 0.2f * t1), av.y, p1);
            p1 = fmaf(fmaxf(t2, 0.2f * t2), av.z, p1);
            p1 = fmaf(fmaxf(t3, 0.2f * t3), av.w, p1);
        }

#pragma unroll
        for (int o = 32; o > 0; o >>= 1) {
            p0 += __shfl_xor(p0, o, 64);
            p1 += __shfl_xor(p1, o, 64);
        }
        if (i + 1 >= end) p1 = -1.0e30f;   // exp -> 0

        float e0 = __expf(p0);
        float e1 = __expf(p1);
        s += e0 + e1;
        a0 = fmaf(e0, x00, fmaf(e1, x10, a0));
        a1 = fmaf(e0, x01, fmaf(e1, x11, a1));
        a2 = fmaf(e0, x02, fmaf(e1, x12, a2));
        a3 = fmaf(e0, x03, fmaf(e1, x13, a3));
    }

    float inv = (end > beg) ? 1.f / s : 0.f;

    ushort4 hv = *(const ushort4*)(hres + (long)n * OUTD + j0);
    float h0 = fmaxf(fmaf(a0, inv, bf2f(hv.x)), 0.f);
    float h1 = fmaxf(fmaf(a1, inv, bf2f(hv.y)), 0.f);
    float h2 = fmaxf(fmaf(a2, inv, bf2f(hv.z)), 0.f);
    float h3 = fmaxf(fmaf(a3, inv, bf2f(hv.w)), 0.f);

    float sum = h0 + h1 + h2 + h3;
    float sq = h0 * h0 + h1 * h1 + h2 * h2 + h3 * h3;
#pragma unroll
    for (int o = 32; o > 0; o >>= 1) {
        sum += __shfl_xor(sum, o, 64);
        sq += __shfl_xor(sq, o, 64);
    }
    float mu = sum * (1.f / OUTD);
    float var = sq * (1.f / OUTD) - mu * mu;
    float rs = rsqrtf(fmaxf(var, 0.f) + 1e-5f);

    float4 gv = *(const float4*)(g2 + j0);
    float4 bv = *(const float4*)(be2 + j0);
    lds[wid][j0 + 0] = (h0 - mu) * rs * gv.x + bv.x;
    lds[wid][j0 + 1] = (h1 - mu) * rs * gv.y + bv.y;
    lds[wid][j0 + 2] = (h2 - mu) * rs * gv.z + bv.z;
    lds[wid][j0 + 3] = (h3 - mu) * rs * gv.w + bv.w;
    __syncthreads();

    if (lane < N_ACT) {
        float qv = bq[lane];
#pragma unroll 4
        for (int j = 0; j < OUTD; j++) qv = fmaf(lds[wid][j], Wq[j * N_ACT + lane], qv);
        out[(long)n * N_ACT + lane] = qv;
    }
}

extern "C" void kernel_launch(void* const* d_in, const int* in_sizes, int n_in,
                              void* d_out, int out_size, void* d_ws, size_t ws_size,
                              hipStream_t stream) {
    (void)in_sizes; (void)n_in; (void)out_size; (void)ws_size;
    const float* inp  = (const float*)d_in[0];
    const int*   ei   = (const int*)d_in[1];
    const float* ea   = (const float*)d_in[2];
    const float* W0   = (const float*)d_in[3];
    const float* b0   = (const float*)d_in[4];
    const float* g0   = (const float*)d_in[5];
    const float* be0  = (const float*)d_in[6];
    const float* W1   = (const float*)d_in[7];
    const float* b1   = (const float*)d_in[8];
    const float* g1   = (const float*)d_in[9];
    const float* be1  = (const float*)d_in[10];
    const float* Wl   = (const float*)d_in[11];
    const float* bl   = (const float*)d_in[12];
    const float* Wr   = (const float*)d_in[13];
    const float* br   = (const float*)d_in[14];
    const float* We   = (const float*)d_in[15];
    const float* att  = (const float*)d_in[16];
    const float* Wres = (const float*)d_in[17];
    const float* gbias= (const float*)d_in[18];
    const float* g2   = (const float*)d_in[19];
    const float* be2  = (const float*)d_in[20];
    const float* Wq   = (const float*)d_in[21];
    const float* bq   = (const float*)d_in[22];
    float* out = (float*)d_out;

    char* ws = (char*)d_ws;
    size_t o = 0;
    auto alloc = [&](size_t bytes) -> void* {
        void* p = ws + o;
        o += (bytes + 255) & ~(size_t)255;
        return p;
    };
    // total ~129 MiB
    u16*   x1     = (u16*)  alloc((size_t)N_NODES * HID * 2);     // 16 MiB
    u16*   xl     = (u16*)  alloc((size_t)N_NODES * OUTD * 2);    // 32 MiB
    u16*   xr     = (u16*)  alloc((size_t)N_NODES * OUTD * 2);    // 32 MiB
    u16*   hres   = (u16*)  alloc((size_t)N_NODES * OUTD * 2);    // 32 MiB
    int*   deg    = (int*)  alloc((size_t)N_NODES * 4);           // 256 KiB
    int*   cursor = (int*)  alloc((size_t)N_NODES * 4);           // 256 KiB (contiguous with deg)
    int*   off    = (int*)  alloc((size_t)(N_NODES + 1) * 4);
    int4*  erec   = (int4*) alloc((size_t)N_EDGES * 16);          // 16 MiB
    u16*   wt     = (u16*)  alloc((size_t)768 * HID * 2);         // 192 KiB, [768][128] n-major bf16

    k_zero<<<(2 * N_NODES) / 256, 256, 0, stream>>>(deg);  // zeroes deg + cursor
    k_deg<<<N_EDGES / 256, 256, 0, stream>>>(ei, deg);
    k_scan<<<1, 1024, 0, stream>>>(deg, off);
    k_scatter<<<N_EDGES / 256, 256, 0, stream>>>(ei, ea, off, cursor, erec);
    k_cvtw<<<(768 * HID) / 256, 256, 0, stream>>>(Wl, Wr, Wres, wt);
    k_mlp<<<N_NODES / NPB_MLP, 128, 0, stream>>>(inp, W0, b0, g0, be0, W1, b1, g1, be1, x1);
    k_proj_mfma<<<dim3(N_NODES / 64, 3), 256, 0, stream>>>(x1, wt, bl, br, gbias, xl, xr, hres);
    k_agg_fused<<<N_NODES / 4, 256, 0, stream>>>(off, erec, xl, xr, hres, We, att, g2, be2, Wq, bq, out);
}